// Round 1
// baseline (33.165 us; speedup 1.0000x reference)
//
#include <hip/hip_runtime.h>

#define NC 1024
#define NS 32
#define DD 512
#define MARGIN 0.3f

// One block per class. 256 threads.
__global__ __launch_bounds__(256) void ccl_per_class(const float* __restrict__ emb,
                                                     float* __restrict__ class_loss) {
    const int c = blockIdx.x;
    const int t = threadIdx.x;
    const float* pos = emb + (size_t)c * (2 * NS * DD);
    const float* neg = pos + NS * DD;

    __shared__ float s_anchor[DD];
    __shared__ float s_ap[NS];
    __shared__ float s_nd[NS];

    // ---- Pass 1: anchor[d] = mean_s pos[s][d] ----
    // 2 groups of 128 threads; group g handles rows s = g, g+2, ...
    // Each thread owns one float4 column (col4 = t & 127). Coalesced 2KB/row.
    const int col4 = t & 127;
    const int g = t >> 7;
    const float4* posv = (const float4*)pos;
    float4 acc = make_float4(0.f, 0.f, 0.f, 0.f);
#pragma unroll
    for (int s = 0; s < NS / 2; ++s) {
        float4 v = posv[(2 * s + g) * (DD / 4) + col4];
        acc.x += v.x; acc.y += v.y; acc.z += v.z; acc.w += v.w;
    }
    if (g == 0) {
        ((float4*)s_anchor)[col4] = acc;
    }
    __syncthreads();
    if (g == 1) {
        float4 o = ((float4*)s_anchor)[col4];
        o.x = (o.x + acc.x) * (1.f / NS);
        o.y = (o.y + acc.y) * (1.f / NS);
        o.z = (o.z + acc.z) * (1.f / NS);
        o.w = (o.w + acc.w) * (1.f / NS);
        ((float4*)s_anchor)[col4] = o;
    }
    __syncthreads();

    // ---- Pass 2: per-sample squared distances to anchor ----
    // thread t: sample s = t>>3, octet lane k = t&7; float4 cols k, k+8, ... (16 iters)
    // Octet of consecutive lanes covers 128B contiguous per row per iter.
    const int s = t >> 3;
    const int k = t & 7;
    const float4* negv = (const float4*)neg;
    const float4* anch = (const float4*)s_anchor;
    float ap = 0.f, nd = 0.f;
#pragma unroll
    for (int i = 0; i < DD / 4 / 8; ++i) {
        const int c4 = k + 8 * i;
        const float4 a = anch[c4];
        float4 p = posv[s * (DD / 4) + c4];
        float dx = p.x - a.x, dy = p.y - a.y, dz = p.z - a.z, dw = p.w - a.w;
        ap += dx * dx + dy * dy + dz * dz + dw * dw;
        float4 n = negv[s * (DD / 4) + c4];
        dx = n.x - a.x; dy = n.y - a.y; dz = n.z - a.z; dw = n.w - a.w;
        nd += dx * dx + dy * dy + dz * dz + dw * dw;
    }
    // reduce across the 8 lanes of the octet (masks 1,2,4 stay in-octet)
#pragma unroll
    for (int m = 1; m < 8; m <<= 1) {
        ap += __shfl_xor(ap, m);
        nd += __shfl_xor(nd, m);
    }
    if (k == 0) { s_ap[s] = ap; s_nd[s] = nd; }
    __syncthreads();

    if (t == 0) {
        float an = s_nd[0];
#pragma unroll
        for (int j = 1; j < NS; ++j) an = fminf(an, s_nd[j]);
        float loss = 0.f;
#pragma unroll
        for (int j = 0; j < NS; ++j) loss += fmaxf(s_ap[j] - an + MARGIN, 0.f);
        class_loss[c] = loss;
    }
}

// Deterministic final reduction: mean of 1024 class losses.
__global__ __launch_bounds__(256) void ccl_reduce(const float* __restrict__ class_loss,
                                                  float* __restrict__ out) {
    const int t = threadIdx.x;
    float v = class_loss[t] + class_loss[t + 256] + class_loss[t + 512] + class_loss[t + 768];
#pragma unroll
    for (int m = 32; m >= 1; m >>= 1) v += __shfl_down(v, m);
    __shared__ float s_partial[4];
    if ((t & 63) == 0) s_partial[t >> 6] = v;
    __syncthreads();
    if (t == 0)
        out[0] = (s_partial[0] + s_partial[1] + s_partial[2] + s_partial[3]) * (1.f / NC);
}

extern "C" void kernel_launch(void* const* d_in, const int* in_sizes, int n_in,
                              void* d_out, int out_size, void* d_ws, size_t ws_size,
                              hipStream_t stream) {
    const float* emb = (const float*)d_in[0];   // (2*NC*NS, DD) f32
    // d_in[1] (target) is unused by the reference computation.
    float* cls = (float*)d_ws;                  // NC floats scratch
    float* out = (float*)d_out;                 // 1 float
    ccl_per_class<<<NC, 256, 0, stream>>>(emb, cls);
    ccl_reduce<<<1, 256, 0, stream>>>(cls, out);
}

// Round 2
// 29.615 us; speedup vs baseline: 1.1199x; 1.1199x over previous
//
#include <hip/hip_runtime.h>

#define NC 1024
#define NS 32
#define DD 512
#define MARGIN 0.3f

// One block per class, 256 threads. Entire 128 KB class tile is loaded into
// registers up front (32x global_load_dwordx4 per thread) -- each byte of
// HBM is read exactly once, no second pass.
//
// Layout: g = t>>7 selects sample parity (rows s = 2j+g), col4 = t&127 is the
// thread's float4 column. Consecutive lanes -> consecutive float4s: perfectly
// coalesced 2 KB per row.
__global__ __launch_bounds__(256) void ccl_per_class(const float* __restrict__ emb,
                                                     float* __restrict__ class_loss) {
    const int c = blockIdx.x;
    const int t = threadIdx.x;
    const int g = t >> 7;
    const int col4 = t & 127;
    const float4* posv = (const float4*)(emb + (size_t)c * (2 * NS * DD));
    const float4* negv = posv + NS * DD / 4;

    __shared__ float4 s_part[2][128];   // per-group column sums
    __shared__ float4 s_anchor[128];    // anchor (float4 columns)
    __shared__ float s_wap[4][16];      // per-wave sample partials (ap)
    __shared__ float s_wnd[4][16];      // per-wave sample partials (nd)

    // ---- load everything: pos first (needed first), then neg ----
    float4 p[16], n[16];
#pragma unroll
    for (int j = 0; j < 16; ++j) p[j] = posv[(2 * j + g) * (DD / 4) + col4];
#pragma unroll
    for (int j = 0; j < 16; ++j) n[j] = negv[(2 * j + g) * (DD / 4) + col4];

    // ---- anchor: thread-local column sum over 16 pos rows, LDS combine ----
    float4 acc = p[0];
#pragma unroll
    for (int j = 1; j < 16; ++j) {
        acc.x += p[j].x; acc.y += p[j].y; acc.z += p[j].z; acc.w += p[j].w;
    }
    s_part[g][col4] = acc;
    __syncthreads();
    if (t < 128) {
        float4 a = s_part[0][t];
        float4 b = s_part[1][t];
        a.x = (a.x + b.x) * (1.f / NS);
        a.y = (a.y + b.y) * (1.f / NS);
        a.z = (a.z + b.z) * (1.f / NS);
        a.w = (a.w + b.w) * (1.f / NS);
        s_anchor[t] = a;
    }
    __syncthreads();

    // ---- per-(sample, column) squared-diff partials ----
    const float4 a = s_anchor[col4];
    float apc[16], ndc[16];
#pragma unroll
    for (int j = 0; j < 16; ++j) {
        float dx = p[j].x - a.x, dy = p[j].y - a.y, dz = p[j].z - a.z, dw = p[j].w - a.w;
        apc[j] = dx * dx + dy * dy + dz * dz + dw * dw;
        dx = n[j].x - a.x; dy = n[j].y - a.y; dz = n[j].z - a.z; dw = n[j].w - a.w;
        ndc[j] = dx * dx + dy * dy + dz * dz + dw * dw;
    }

    // ---- reduce across columns: 64-lane butterfly (each wave covers 64 cols) ----
#pragma unroll
    for (int m = 1; m < 64; m <<= 1) {
#pragma unroll
        for (int j = 0; j < 16; ++j) {
            apc[j] += __shfl_xor(apc[j], m);
            ndc[j] += __shfl_xor(ndc[j], m);
        }
    }
    const int wv = t >> 6;
    if ((t & 63) == 0) {
#pragma unroll
        for (int j = 0; j < 16; ++j) { s_wap[wv][j] = apc[j]; s_wnd[wv][j] = ndc[j]; }
    }
    __syncthreads();

    // ---- combine the two waves of each group; min + hinge in wave 0 ----
    if (t < NS) {
        const int sg = t & 1, sj = t >> 1;  // sample s = 2*sj + sg
        float ap = s_wap[2 * sg][sj] + s_wap[2 * sg + 1][sj];
        float nd = s_wnd[2 * sg][sj] + s_wnd[2 * sg + 1][sj];
        float an = nd;
#pragma unroll
        for (int m = 1; m < 32; m <<= 1) an = fminf(an, __shfl_xor(an, m));
        float l = fmaxf(ap - an + MARGIN, 0.f);
#pragma unroll
        for (int m = 1; m < 32; m <<= 1) l += __shfl_xor(l, m);
        if (t == 0) class_loss[c] = l;
    }
}

// Deterministic final reduction: mean of 1024 class losses.
__global__ __launch_bounds__(256) void ccl_reduce(const float* __restrict__ class_loss,
                                                  float* __restrict__ out) {
    const int t = threadIdx.x;
    float v = class_loss[t] + class_loss[t + 256] + class_loss[t + 512] + class_loss[t + 768];
#pragma unroll
    for (int m = 32; m >= 1; m >>= 1) v += __shfl_down(v, m);
    __shared__ float s_partial[4];
    if ((t & 63) == 0) s_partial[t >> 6] = v;
    __syncthreads();
    if (t == 0)
        out[0] = (s_partial[0] + s_partial[1] + s_partial[2] + s_partial[3]) * (1.f / NC);
}

extern "C" void kernel_launch(void* const* d_in, const int* in_sizes, int n_in,
                              void* d_out, int out_size, void* d_ws, size_t ws_size,
                              hipStream_t stream) {
    const float* emb = (const float*)d_in[0];   // (2*NC*NS, DD) f32
    float* cls = (float*)d_ws;                  // NC floats scratch
    float* out = (float*)d_out;                 // 1 float
    ccl_per_class<<<NC, 256, 0, stream>>>(emb, cls);
    ccl_reduce<<<1, 256, 0, stream>>>(cls, out);
}